// Round 1
// baseline (613.209 us; speedup 1.0000x reference)
//
#include <hip/hip_runtime.h>
#include <stdint.h>

#define N_NODES 4096
#define NNN ((int64_t)N_NODES * (int64_t)N_NODES)
#define NC 12
// floor(0.9 * (N*N - 1)) = floor(0.9 * 16777215) = 15099493 (frac = 0.5)
#define K0_RANK 15099493u

static __device__ __forceinline__ uint32_t f2key(float f) {
    uint32_t x = __float_as_uint(f);
    return (x & 0x80000000u) ? ~x : (x | 0x80000000u);
}
static __device__ __forceinline__ float key2f(uint32_t k) {
    uint32_t x = (k & 0x80000000u) ? (k & 0x7FFFFFFFu) : ~k;
    return __uint_as_float(x);
}

// ---------------------------------------------------------------------------
// 1) agg[u,v] = sum_c w[c] * attn[c,u,v] + b   (805MB read, 67MB write)
// ---------------------------------------------------------------------------
__global__ void agg_kernel(const float* __restrict__ attn,
                           const float* __restrict__ w,
                           const float* __restrict__ bb,
                           float* __restrict__ agg) {
    float wr[NC];
#pragma unroll
    for (int c = 0; c < NC; ++c) wr[c] = w[c];
    float b0 = bb[0];
    const float4* a4 = (const float4*)attn;
    float4* o4 = (float4*)agg;
    int64_t total = NNN / 4;
    int64_t stride = (int64_t)gridDim.x * blockDim.x;
    for (int64_t i = (int64_t)blockIdx.x * blockDim.x + threadIdx.x; i < total; i += stride) {
        float ax = b0, ay = b0, az = b0, aw = b0;
#pragma unroll
        for (int c = 0; c < NC; ++c) {
            float4 t = a4[(int64_t)c * (NNN / 4) + i];
            ax += wr[c] * t.x; ay += wr[c] * t.y; az += wr[c] * t.z; aw += wr[c] * t.w;
        }
        o4[i] = make_float4(ax, ay, az, aw);
    }
}

// ---------------------------------------------------------------------------
// 2) Radix select: hist over 12 / 12 / 8 bits of the order-preserving key.
// sel layout: [0]=prefix1 [1]=rank1 [2]=prefix2 [3]=rank2 [4]=key0
//             [5]=count_le [6]=minkey_gt [7]=thresh(float bits)
// ---------------------------------------------------------------------------
template <int LEVEL>
__global__ void hist_kernel(const float* __restrict__ agg,
                            const uint32_t* __restrict__ sel,
                            uint32_t* __restrict__ hist) {
    __shared__ uint32_t h[4096];
    const int nb = (LEVEL == 3) ? 256 : 4096;
    for (int i = threadIdx.x; i < nb; i += blockDim.x) h[i] = 0;
    uint32_t p1 = 0, p24 = 0;
    if (LEVEL == 2) p1 = sel[0];
    if (LEVEL == 3) p24 = (sel[0] << 12) | sel[2];
    __syncthreads();
    const float4* a4 = (const float4*)agg;
    int64_t total = NNN / 4;
    int64_t stride = (int64_t)gridDim.x * blockDim.x;
    for (int64_t i = (int64_t)blockIdx.x * blockDim.x + threadIdx.x; i < total; i += stride) {
        float4 v = a4[i];
        float f[4] = {v.x, v.y, v.z, v.w};
#pragma unroll
        for (int j = 0; j < 4; ++j) {
            uint32_t k = f2key(f[j]);
            if (LEVEL == 1) atomicAdd(&h[k >> 20], 1u);
            else if (LEVEL == 2) { if ((k >> 20) == p1) atomicAdd(&h[(k >> 8) & 0xFFFu], 1u); }
            else { if ((k >> 8) == p24) atomicAdd(&h[k & 0xFFu], 1u); }
        }
    }
    __syncthreads();
    for (int i = threadIdx.x; i < nb; i += blockDim.x) {
        uint32_t c = h[i];
        if (c) atomicAdd(&hist[i], c);
    }
}

template <int LEVEL>
__global__ void scan_kernel(const uint32_t* __restrict__ hist, uint32_t* __restrict__ sel) {
    const int nb = (LEVEL == 3) ? 256 : 4096;
    const int per = nb / 256;
    __shared__ uint32_t hloc[4096];
    __shared__ uint32_t sc[256];
    int t = threadIdx.x;
    for (int i = t; i < nb; i += 256) hloc[i] = hist[i];
    __syncthreads();
    uint32_t target = (LEVEL == 1) ? K0_RANK : sel[(LEVEL == 2) ? 1 : 3];
    uint32_t p = 0;
    for (int i = 0; i < per; ++i) p += hloc[t * per + i];
    sc[t] = p;
    __syncthreads();
    for (int d = 1; d < 256; d <<= 1) {
        uint32_t v = (t >= d) ? sc[t - d] : 0u;
        __syncthreads();
        sc[t] += v;
        __syncthreads();
    }
    uint32_t excl = sc[t] - p;
    if (p > 0 && target >= excl && target < excl + p) {
        uint32_t cum = excl;
        int b = t * per;
        while (cum + hloc[b] <= target) { cum += hloc[b]; ++b; }
        if (LEVEL == 1)      { sel[0] = (uint32_t)b; sel[1] = target - cum; }
        else if (LEVEL == 2) { sel[2] = (uint32_t)b; sel[3] = target - cum; }
        else                 { sel[4] = (sel[0] << 20) | (sel[2] << 8) | (uint32_t)b; }
    }
}

__global__ void count_kernel(const float* __restrict__ agg, uint32_t* __restrict__ sel) {
    uint32_t key0 = sel[4];
    uint32_t c = 0, mn = 0xFFFFFFFFu;
    const float4* a4 = (const float4*)agg;
    int64_t total = NNN / 4;
    int64_t stride = (int64_t)gridDim.x * blockDim.x;
    for (int64_t i = (int64_t)blockIdx.x * blockDim.x + threadIdx.x; i < total; i += stride) {
        float4 v = a4[i];
        float f[4] = {v.x, v.y, v.z, v.w};
#pragma unroll
        for (int j = 0; j < 4; ++j) {
            uint32_t k = f2key(f[j]);
            if (k <= key0) ++c;
            else mn = min(mn, k);
        }
    }
    __shared__ uint32_t cs, ms;
    if (threadIdx.x == 0) { cs = 0; ms = 0xFFFFFFFFu; }
    __syncthreads();
    atomicAdd(&cs, c);
    atomicMin(&ms, mn);
    __syncthreads();
    if (threadIdx.x == 0) {
        atomicAdd(&sel[5], cs);
        atomicMin(&sel[6], ms);
    }
}

__global__ void thresh_kernel(uint32_t* __restrict__ sel) {
    float v0 = key2f(sel[4]);
    // v[k0+1] == v0 if at least k0+2 elements are <= key0, else next larger key
    float v1 = (sel[5] >= K0_RANK + 2u) ? v0 : key2f(sel[6]);
    ((float*)sel)[7] = v0 + 0.5f * (v1 - v0);
}

// ---------------------------------------------------------------------------
// 3) B[v][u] bitmask of A^T  (A = mask | I), built per 64x64 tile via ballot
// ---------------------------------------------------------------------------
__global__ void maskB_kernel(const float* __restrict__ agg,
                             const uint32_t* __restrict__ sel,
                             uint32_t* __restrict__ B) {
    __shared__ uint32_t tile[64][2];
    const float thresh = __uint_as_float(sel[7]);
    int u0 = blockIdx.x * 64, v0 = blockIdx.y * 64;
    int wave = threadIdx.x >> 6, lane = threadIdx.x & 63;
    for (int i = 0; i < 16; ++i) {
        int r = wave * 16 + i;
        int u = u0 + r, v = v0 + lane;
        float val = agg[(int64_t)u * N_NODES + v];
        bool pred = (val >= thresh) || (u == v);
        unsigned long long bm = __ballot(pred ? 1 : 0);
        if (lane == 0) { tile[r][0] = (uint32_t)bm; tile[r][1] = (uint32_t)(bm >> 32); }
    }
    __syncthreads();
    int t = threadIdx.x;
    if (t < 64) {
        int v = v0 + t;
        int sh = t & 31, hw = t >> 5;
        uint32_t w0 = 0, w1 = 0;
#pragma unroll
        for (int i = 0; i < 32; ++i) {
            w0 |= ((tile[i][hw] >> sh) & 1u) << i;
            w1 |= ((tile[32 + i][hw] >> sh) & 1u) << i;
        }
        B[(int64_t)v * (N_NODES / 32) + (u0 >> 5)]     = w0;
        B[(int64_t)v * (N_NODES / 32) + (u0 >> 5) + 1] = w1;
    }
}

// deg[v] = popcount(B row v);  s[v] = 1/sqrt(deg)  (deg >= 1 via self-loop)
__global__ void degs_kernel(const uint32_t* __restrict__ B, float* __restrict__ s) {
    int v = blockIdx.x * blockDim.x + threadIdx.x;
    const uint4* row = (const uint4*)(B + (int64_t)v * (N_NODES / 32));
    uint32_t d = 0;
#pragma unroll
    for (int i = 0; i < 32; ++i) {
        uint4 q = row[i];
        d += __popc(q.x) + __popc(q.y) + __popc(q.z) + __popc(q.w);
    }
    s[v] = 1.0f / sqrtf((float)d);
}

// ---------------------------------------------------------------------------
// 4) GCN layers: g = s * (x @ W); h = relu(s * (B-gather of g) + b)
// ---------------------------------------------------------------------------
__global__ void gemm1_kernel(const float* __restrict__ x, const float* __restrict__ W1,
                             const float* __restrict__ s, float* __restrict__ g) {
    __shared__ float xr[128];
    int u = blockIdx.x, j = threadIdx.x;  // 256 threads
    if (j < 128) xr[j] = x[u * 128 + j];
    __syncthreads();
    float acc = 0.f;
#pragma unroll 8
    for (int k = 0; k < 128; ++k) acc += xr[k] * W1[k * 256 + j];
    g[(int64_t)u * 256 + j] = s[u] * acc;
}

__global__ void spmm1_kernel(const uint32_t* __restrict__ B, const float* __restrict__ g,
                             const float* __restrict__ s, const float* __restrict__ b1,
                             float* __restrict__ h1) {
    __shared__ uint32_t row[128];
    int v = blockIdx.x, j = threadIdx.x;  // 256 threads
    if (j < 128) row[j] = B[(int64_t)v * 128 + j];
    __syncthreads();
    float acc = 0.f;
    for (int w = 0; w < 128; ++w) {
        uint32_t m = row[w];
        while (m) {
            int u = w * 32 + __ffs(m) - 1;
            m &= m - 1;
            acc += g[(int64_t)u * 256 + j];
        }
    }
    h1[(int64_t)v * 256 + j] = fmaxf(s[v] * acc + b1[j], 0.0f);
}

__global__ void gemm2_kernel(const float* __restrict__ h1, const float* __restrict__ W2,
                             const float* __restrict__ s, float* __restrict__ g2) {
    __shared__ float hr[256];
    int u = blockIdx.x, j = threadIdx.x;  // 128 threads
    hr[j] = h1[(int64_t)u * 256 + j];
    hr[j + 128] = h1[(int64_t)u * 256 + j + 128];
    __syncthreads();
    float acc = 0.f;
#pragma unroll 8
    for (int k = 0; k < 256; ++k) acc += hr[k] * W2[k * 128 + j];
    g2[(int64_t)u * 128 + j] = s[u] * acc;
}

__global__ void spmm2_kernel(const uint32_t* __restrict__ B, const float* __restrict__ g2,
                             const float* __restrict__ s, const float* __restrict__ b2,
                             float* __restrict__ out) {
    __shared__ uint32_t row[128];
    int v = blockIdx.x, j = threadIdx.x;  // 128 threads
    row[j] = B[(int64_t)v * 128 + j];
    __syncthreads();
    float acc = 0.f;
    for (int w = 0; w < 128; ++w) {
        uint32_t m = row[w];
        while (m) {
            int u = w * 32 + __ffs(m) - 1;
            m &= m - 1;
            acc += g2[(int64_t)u * 128 + j];
        }
    }
    out[(int64_t)v * 128 + j] = s[v] * acc + b2[j];
}

// ---------------------------------------------------------------------------
extern "C" void kernel_launch(void* const* d_in, const int* in_sizes, int n_in,
                              void* d_out, int out_size, void* d_ws, size_t ws_size,
                              hipStream_t stream) {
    const float* x    = (const float*)d_in[0];
    const float* attn = (const float*)d_in[1];
    const float* aggw = (const float*)d_in[2];
    const float* aggb = (const float*)d_in[3];
    const float* W1   = (const float*)d_in[4];
    const float* b1   = (const float*)d_in[5];
    const float* W2   = (const float*)d_in[6];
    const float* b2   = (const float*)d_in[7];
    float* out = (float*)d_out;

    char* ws = (char*)d_ws;
    size_t OFF_AGG = 0;
    size_t OFF_H1  = OFF_AGG + (size_t)NNN * 4;            // 67,108,864
    size_t OFF_H2  = OFF_H1 + 4096 * 4;
    size_t OFF_H3  = OFF_H2 + 4096 * 4;
    size_t OFF_SEL = OFF_H3 + 256 * 4;
    size_t OFF_B   = OFF_SEL + 256;                        // keep 256B alignment
    size_t OFF_S   = OFF_B + (size_t)N_NODES * (N_NODES / 32) * 4;  // 2MB bitmask
    size_t OFF_G   = OFF_S + (size_t)N_NODES * 4;
    size_t OFF_H1T = OFF_G + (size_t)N_NODES * 256 * 4;
    size_t OFF_G2  = OFF_H1T + (size_t)N_NODES * 256 * 4;

    float*    agg   = (float*)(ws + OFF_AGG);
    uint32_t* hist1 = (uint32_t*)(ws + OFF_H1);
    uint32_t* hist2 = (uint32_t*)(ws + OFF_H2);
    uint32_t* hist3 = (uint32_t*)(ws + OFF_H3);
    uint32_t* sel   = (uint32_t*)(ws + OFF_SEL);
    uint32_t* Bm    = (uint32_t*)(ws + OFF_B);
    float*    s     = (float*)(ws + OFF_S);
    float*    g     = (float*)(ws + OFF_G);
    float*    h1    = (float*)(ws + OFF_H1T);
    float*    g2    = (float*)(ws + OFF_G2);

    // per-call init (harness does not re-poison between replays)
    hipMemsetAsync(hist1, 0, (4096 + 4096 + 256) * 4, stream);
    hipMemsetAsync(&sel[5], 0, 4, stream);
    hipMemsetAsync(&sel[6], 0xFF, 4, stream);

    agg_kernel<<<2048, 256, 0, stream>>>(attn, aggw, aggb, agg);
    hist_kernel<1><<<512, 256, 0, stream>>>(agg, sel, hist1);
    scan_kernel<1><<<1, 256, 0, stream>>>(hist1, sel);
    hist_kernel<2><<<512, 256, 0, stream>>>(agg, sel, hist2);
    scan_kernel<2><<<1, 256, 0, stream>>>(hist2, sel);
    hist_kernel<3><<<512, 256, 0, stream>>>(agg, sel, hist3);
    scan_kernel<3><<<1, 256, 0, stream>>>(hist3, sel);
    count_kernel<<<512, 256, 0, stream>>>(agg, sel);
    thresh_kernel<<<1, 1, 0, stream>>>(sel);

    dim3 mg(N_NODES / 64, N_NODES / 64);
    maskB_kernel<<<mg, 256, 0, stream>>>(agg, sel, Bm);
    degs_kernel<<<N_NODES / 256, 256, 0, stream>>>(Bm, s);

    gemm1_kernel<<<N_NODES, 256, 0, stream>>>(x, W1, s, g);
    spmm1_kernel<<<N_NODES, 256, 0, stream>>>(Bm, g, s, b1, h1);
    gemm2_kernel<<<N_NODES, 128, 0, stream>>>(h1, W2, s, g2);
    spmm2_kernel<<<N_NODES, 128, 0, stream>>>(Bm, g2, s, b2, out);
}

// Round 2
// 440.699 us; speedup vs baseline: 1.3914x; 1.3914x over previous
//
#include <hip/hip_runtime.h>
#include <stdint.h>

#define N_NODES 4096
#define NNN ((int64_t)N_NODES * (int64_t)N_NODES)
#define NC 12
// floor(0.9 * (N*N - 1)) = 15099493 (frac = 0.5)
#define K0_RANK 15099493u

static __device__ __forceinline__ uint32_t f2key(float f) {
    uint32_t x = __float_as_uint(f);
    return (x & 0x80000000u) ? ~x : (x | 0x80000000u);
}
static __device__ __forceinline__ float key2f(uint32_t k) {
    uint32_t x = (k & 0x80000000u) ? (k & 0x7FFFFFFFu) : ~k;
    return __uint_as_float(x);
}

// ---------------------------------------------------------------------------
// 1) agg = sum_c w[c]*attn[c] + b   (805MB read, 67MB write) + fused 12-bit hist
// ---------------------------------------------------------------------------
__global__ void agg_kernel(const float* __restrict__ attn,
                           const float* __restrict__ w,
                           const float* __restrict__ bb,
                           float* __restrict__ agg,
                           uint32_t* __restrict__ hist1) {
    __shared__ uint32_t h[4096];
    for (int i = threadIdx.x; i < 4096; i += blockDim.x) h[i] = 0;
    float wr[NC];
#pragma unroll
    for (int c = 0; c < NC; ++c) wr[c] = w[c];
    float b0 = bb[0];
    __syncthreads();
    const float4* a4 = (const float4*)attn;
    float4* o4 = (float4*)agg;
    int64_t total = NNN / 4;
    int64_t stride = (int64_t)gridDim.x * blockDim.x;
    for (int64_t i = (int64_t)blockIdx.x * blockDim.x + threadIdx.x; i < total; i += stride) {
        float ax = b0, ay = b0, az = b0, aw = b0;
#pragma unroll
        for (int c = 0; c < NC; ++c) {
            float4 t = a4[(int64_t)c * (NNN / 4) + i];
            ax += wr[c] * t.x; ay += wr[c] * t.y; az += wr[c] * t.z; aw += wr[c] * t.w;
        }
        o4[i] = make_float4(ax, ay, az, aw);
        atomicAdd(&h[f2key(ax) >> 20], 1u);
        atomicAdd(&h[f2key(ay) >> 20], 1u);
        atomicAdd(&h[f2key(az) >> 20], 1u);
        atomicAdd(&h[f2key(aw) >> 20], 1u);
    }
    __syncthreads();
    for (int i = threadIdx.x; i < 4096; i += blockDim.x) {
        uint32_t c = h[i];
        if (c) atomicAdd(&hist1[i], c);
    }
}

// ---------------------------------------------------------------------------
// 2) level-2 hist (next 12 bits within selected level-1 bin)
// ---------------------------------------------------------------------------
__global__ void hist2_kernel(const float* __restrict__ agg,
                             const uint32_t* __restrict__ sel,
                             uint32_t* __restrict__ hist) {
    __shared__ uint32_t h[4096];
    for (int i = threadIdx.x; i < 4096; i += blockDim.x) h[i] = 0;
    uint32_t p1 = sel[0];
    __syncthreads();
    const float4* a4 = (const float4*)agg;
    int64_t total = NNN / 4;
    int64_t stride = (int64_t)gridDim.x * blockDim.x;
    for (int64_t i = (int64_t)blockIdx.x * blockDim.x + threadIdx.x; i < total; i += stride) {
        float4 v = a4[i];
        float f[4] = {v.x, v.y, v.z, v.w};
#pragma unroll
        for (int j = 0; j < 4; ++j) {
            uint32_t k = f2key(f[j]);
            if ((k >> 20) == p1) atomicAdd(&h[(k >> 8) & 0xFFFu], 1u);
        }
    }
    __syncthreads();
    for (int i = threadIdx.x; i < 4096; i += blockDim.x) {
        uint32_t c = h[i];
        if (c) atomicAdd(&hist[i], c);
    }
}

// ---------------------------------------------------------------------------
// Pass C: level-3 hist (low 8 bits within selected prefix24) + min key > prefix24
// ---------------------------------------------------------------------------
__global__ void passC_kernel(const float* __restrict__ agg,
                             uint32_t* __restrict__ sel,
                             uint32_t* __restrict__ hist3) {
    __shared__ uint32_t h[256];
    __shared__ uint32_t ms;
    if (threadIdx.x == 0) ms = 0xFFFFFFFFu;
    for (int i = threadIdx.x; i < 256; i += blockDim.x) h[i] = 0;
    uint32_t p24 = (sel[0] << 12) | sel[2];
    __syncthreads();
    uint32_t mn = 0xFFFFFFFFu;
    const float4* a4 = (const float4*)agg;
    int64_t total = NNN / 4;
    int64_t stride = (int64_t)gridDim.x * blockDim.x;
    for (int64_t i = (int64_t)blockIdx.x * blockDim.x + threadIdx.x; i < total; i += stride) {
        float4 v = a4[i];
        float f[4] = {v.x, v.y, v.z, v.w};
#pragma unroll
        for (int j = 0; j < 4; ++j) {
            uint32_t k = f2key(f[j]);
            uint32_t hi = k >> 8;
            if (hi == p24) atomicAdd(&h[k & 0xFFu], 1u);
            else if (hi > p24) mn = min(mn, k);
        }
    }
    atomicMin(&ms, mn);
    __syncthreads();
    for (int i = threadIdx.x; i < 256; i += blockDim.x) {
        uint32_t c = h[i];
        if (c) atomicAdd(&hist3[i], c);
    }
    if (threadIdx.x == 0) atomicMin(&sel[6], ms);
}

// ---------------------------------------------------------------------------
// scans: level 1/2 over 4096 bins
// ---------------------------------------------------------------------------
template <int LEVEL>
__global__ void scan_kernel(const uint32_t* __restrict__ hist, uint32_t* __restrict__ sel) {
    __shared__ uint32_t hloc[4096];
    __shared__ uint32_t sc[256];
    int t = threadIdx.x;
    for (int i = t; i < 4096; i += 256) hloc[i] = hist[i];
    __syncthreads();
    uint32_t target = (LEVEL == 1) ? K0_RANK : sel[1];
    uint32_t p = 0;
#pragma unroll
    for (int i = 0; i < 16; ++i) p += hloc[t * 16 + i];
    sc[t] = p;
    __syncthreads();
    for (int d = 1; d < 256; d <<= 1) {
        uint32_t v = (t >= d) ? sc[t - d] : 0u;
        __syncthreads();
        sc[t] += v;
        __syncthreads();
    }
    uint32_t excl = sc[t] - p;
    if (p > 0 && target >= excl && target < excl + p) {
        uint32_t cum = excl;
        int b = t * 16;
        while (cum + hloc[b] <= target) { cum += hloc[b]; ++b; }
        if (LEVEL == 1) { sel[0] = (uint32_t)b; sel[1] = target - cum; }
        else            { sel[2] = (uint32_t)b; sel[3] = target - cum; }
    }
}

// level-3 scan + threshold computation (exact keys; neighbor from hist3 or mgt)
__global__ void scan3_kernel(const uint32_t* __restrict__ hist3, uint32_t* __restrict__ sel) {
    __shared__ uint32_t h[256];
    h[threadIdx.x] = hist3[threadIdx.x];
    __syncthreads();
    if (threadIdx.x == 0) {
        uint32_t target = sel[3];
        uint32_t cum = 0; int b = 0;
        while (cum + h[b] <= target) { cum += h[b]; ++b; }
        uint32_t p24 = (sel[0] << 12) | sel[2];
        uint32_t key0 = (p24 << 8) | (uint32_t)b;
        uint32_t count_le = K0_RANK - target + cum + h[b];
        uint32_t key1;
        if (count_le >= K0_RANK + 2u) key1 = key0;
        else {
            int nb = b + 1;
            while (nb < 256 && h[nb] == 0) ++nb;
            key1 = (nb < 256) ? ((p24 << 8) | (uint32_t)nb) : sel[6];
        }
        float v0 = key2f(key0);
        float v1 = key2f(key1);
        ((float*)sel)[7] = v0 + 0.5f * (v1 - v0);   // same formula as R1 (passed)
    }
}

// ---------------------------------------------------------------------------
// 3) B[v][u] bitmask of A^T  (A = mask | I)
// ---------------------------------------------------------------------------
__global__ void maskB_kernel(const float* __restrict__ agg,
                             const uint32_t* __restrict__ sel,
                             uint32_t* __restrict__ B) {
    __shared__ uint32_t tile[64][2];
    const float thresh = __uint_as_float(sel[7]);
    int u0 = blockIdx.x * 64, v0 = blockIdx.y * 64;
    int wave = threadIdx.x >> 6, lane = threadIdx.x & 63;
    for (int i = 0; i < 16; ++i) {
        int r = wave * 16 + i;
        int u = u0 + r, v = v0 + lane;
        float val = agg[(int64_t)u * N_NODES + v];
        bool pred = (val >= thresh) || (u == v);
        unsigned long long bm = __ballot(pred ? 1 : 0);
        if (lane == 0) { tile[r][0] = (uint32_t)bm; tile[r][1] = (uint32_t)(bm >> 32); }
    }
    __syncthreads();
    int t = threadIdx.x;
    if (t < 64) {
        int v = v0 + t;
        int sh = t & 31, hw = t >> 5;
        uint32_t w0 = 0, w1 = 0;
#pragma unroll
        for (int i = 0; i < 32; ++i) {
            w0 |= ((tile[i][hw] >> sh) & 1u) << i;
            w1 |= ((tile[32 + i][hw] >> sh) & 1u) << i;
        }
        B[(int64_t)v * (N_NODES / 32) + (u0 >> 5)]     = w0;
        B[(int64_t)v * (N_NODES / 32) + (u0 >> 5) + 1] = w1;
    }
}

// deg[v] = popcount(B row v); s[v]=rsqrt(deg). 4 rows per 256-thread block, coalesced.
__global__ void degs_kernel(const uint32_t* __restrict__ B, float* __restrict__ s) {
    int t = threadIdx.x & 63;
    int v = blockIdx.x * 4 + (threadIdx.x >> 6);
    uint2 q = ((const uint2*)(B + (int64_t)v * 128))[t];
    uint32_t d = __popc(q.x) + __popc(q.y);
#pragma unroll
    for (int o = 1; o < 64; o <<= 1) d += __shfl_xor((int)d, o);
    if (t == 0) s[v] = rsqrtf((float)d);
}

// ---------------------------------------------------------------------------
// 4) gemms: 16 rows per block, x/h1 staged in LDS, W read once per block
// ---------------------------------------------------------------------------
__global__ __launch_bounds__(256) void gemm1_kernel(const float* __restrict__ x,
        const float* __restrict__ W1, const float* __restrict__ s, float* __restrict__ g) {
    __shared__ float xr[2048];    // 16 x 128
    __shared__ float sr[16];
    int u0 = blockIdx.x * 16;
    int t = threadIdx.x;
    const float4* x4 = (const float4*)(x + (int64_t)u0 * 128);
    float4* xr4 = (float4*)xr;
    xr4[t] = x4[t];
    xr4[t + 256] = x4[t + 256];
    if (t < 16) sr[t] = s[u0 + t];
    __syncthreads();
    float acc[16];
#pragma unroll
    for (int r = 0; r < 16; ++r) acc[r] = 0.f;
    for (int k = 0; k < 128; ++k) {
        float wv = W1[k * 256 + t];
#pragma unroll
        for (int r = 0; r < 16; ++r) acc[r] += xr[r * 128 + k] * wv;
    }
#pragma unroll
    for (int r = 0; r < 16; ++r)
        g[(int64_t)(u0 + r) * 256 + t] = sr[r] * acc[r];
}

__global__ __launch_bounds__(128) void gemm2_kernel(const float* __restrict__ h1,
        const float* __restrict__ W2, const float* __restrict__ s, float* __restrict__ g2) {
    __shared__ float hr[4096];    // 16 x 256
    __shared__ float sr[16];
    int u0 = blockIdx.x * 16;
    int t = threadIdx.x;
    const float4* h4 = (const float4*)(h1 + (int64_t)u0 * 256);
    float4* hr4 = (float4*)hr;
#pragma unroll
    for (int i = 0; i < 8; ++i) hr4[t + 128 * i] = h4[t + 128 * i];
    if (t < 16) sr[t] = s[u0 + t];
    __syncthreads();
    float acc[16];
#pragma unroll
    for (int r = 0; r < 16; ++r) acc[r] = 0.f;
    for (int k = 0; k < 256; ++k) {
        float wv = W2[k * 128 + t];
#pragma unroll
        for (int r = 0; r < 16; ++r) acc[r] += hr[r * 256 + k] * wv;
    }
#pragma unroll
    for (int r = 0; r < 16; ++r)
        g2[(int64_t)(u0 + r) * 128 + t] = sr[r] * acc[r];
}

// ---------------------------------------------------------------------------
// 5) spmm: decode bitmask row ONCE into LDS u16 index list, then float4 gather
// ---------------------------------------------------------------------------
static __device__ __forceinline__ uint32_t build_idx(const uint32_t* __restrict__ B,
                                                     int v, int t, uint16_t* idx) {
    const uint32_t* row = B + (int64_t)v * 128;
    uint32_t w0 = row[t], w1 = row[t + 64];
    uint32_t pc0 = __popc(w0), pc1 = __popc(w1);
    int s0 = (int)pc0, s1 = (int)pc1;
#pragma unroll
    for (int d = 1; d < 64; d <<= 1) {
        int a = __shfl_up(s0, d);
        int b = __shfl_up(s1, d);
        if (t >= d) { s0 += a; s1 += b; }
    }
    uint32_t tot0 = (uint32_t)__shfl(s0, 63);
    uint32_t cnt  = tot0 + (uint32_t)__shfl(s1, 63);
    uint32_t p = (uint32_t)s0 - pc0;
    uint32_t m = w0;
    int ub = t * 32;
    while (m) { int bi = __ffs(m) - 1; m &= m - 1; idx[p++] = (uint16_t)(ub + bi); }
    p = tot0 + (uint32_t)s1 - pc1;
    m = w1;
    ub = (t + 64) * 32;
    while (m) { int bi = __ffs(m) - 1; m &= m - 1; idx[p++] = (uint16_t)(ub + bi); }
    __syncthreads();
    return cnt;
}

__global__ __launch_bounds__(64) void spmm1_kernel(const uint32_t* __restrict__ B,
        const float* __restrict__ g, const float* __restrict__ s,
        const float* __restrict__ b1, float* __restrict__ h1) {
    __shared__ uint16_t idx[4096];
    int v = blockIdx.x;
    int t = threadIdx.x;
    uint32_t cnt = build_idx(B, v, t, idx);
    const float4* g4 = (const float4*)g;
    float4 acc = make_float4(0.f, 0.f, 0.f, 0.f);
    uint32_t i = 0;
    for (; i + 4 <= cnt; i += 4) {
        int u0 = idx[i], u1 = idx[i + 1], u2 = idx[i + 2], u3 = idx[i + 3];
        float4 a = g4[u0 * 64 + t];
        float4 b = g4[u1 * 64 + t];
        float4 c = g4[u2 * 64 + t];
        float4 d = g4[u3 * 64 + t];
        acc.x += (a.x + b.x) + (c.x + d.x);
        acc.y += (a.y + b.y) + (c.y + d.y);
        acc.z += (a.z + b.z) + (c.z + d.z);
        acc.w += (a.w + b.w) + (c.w + d.w);
    }
    for (; i < cnt; ++i) {
        float4 a = g4[idx[i] * 64 + t];
        acc.x += a.x; acc.y += a.y; acc.z += a.z; acc.w += a.w;
    }
    float sv = s[v];
    float4 bb = ((const float4*)b1)[t];
    float4 r;
    r.x = fmaxf(sv * acc.x + bb.x, 0.f);
    r.y = fmaxf(sv * acc.y + bb.y, 0.f);
    r.z = fmaxf(sv * acc.z + bb.z, 0.f);
    r.w = fmaxf(sv * acc.w + bb.w, 0.f);
    ((float4*)h1)[(int64_t)v * 64 + t] = r;
}

__global__ __launch_bounds__(64) void spmm2_kernel(const uint32_t* __restrict__ B,
        const float* __restrict__ g2, const float* __restrict__ s,
        const float* __restrict__ b2, float* __restrict__ out) {
    __shared__ uint16_t idx[4096];
    int v = blockIdx.x;
    int t = threadIdx.x;
    uint32_t cnt = build_idx(B, v, t, idx);
    const float4* g4 = (const float4*)g2;
    int jg = t & 31;
    float4 acc = make_float4(0.f, 0.f, 0.f, 0.f);
    for (uint32_t i = (uint32_t)(t >> 5); i < cnt; i += 2) {
        float4 a = g4[idx[i] * 32 + jg];
        acc.x += a.x; acc.y += a.y; acc.z += a.z; acc.w += a.w;
    }
    acc.x += __shfl_xor(acc.x, 32);
    acc.y += __shfl_xor(acc.y, 32);
    acc.z += __shfl_xor(acc.z, 32);
    acc.w += __shfl_xor(acc.w, 32);
    if (t < 32) {
        float sv = s[v];
        float4 bb = ((const float4*)b2)[jg];
        float4 r;
        r.x = sv * acc.x + bb.x;
        r.y = sv * acc.y + bb.y;
        r.z = sv * acc.z + bb.z;
        r.w = sv * acc.w + bb.w;
        ((float4*)out)[(int64_t)v * 32 + jg] = r;
    }
}

// ---------------------------------------------------------------------------
extern "C" void kernel_launch(void* const* d_in, const int* in_sizes, int n_in,
                              void* d_out, int out_size, void* d_ws, size_t ws_size,
                              hipStream_t stream) {
    const float* x    = (const float*)d_in[0];
    const float* attn = (const float*)d_in[1];
    const float* aggw = (const float*)d_in[2];
    const float* aggb = (const float*)d_in[3];
    const float* W1   = (const float*)d_in[4];
    const float* b1   = (const float*)d_in[5];
    const float* W2   = (const float*)d_in[6];
    const float* b2   = (const float*)d_in[7];
    float* out = (float*)d_out;

    char* ws = (char*)d_ws;
    size_t OFF_AGG = 0;
    size_t OFF_H1  = OFF_AGG + (size_t)NNN * 4;
    size_t OFF_H2  = OFF_H1 + 4096 * 4;
    size_t OFF_H3  = OFF_H2 + 4096 * 4;
    size_t OFF_SEL = OFF_H3 + 1024;            // hist3 = 256*4
    size_t OFF_B   = OFF_SEL + 256;
    size_t OFF_S   = OFF_B + (size_t)N_NODES * (N_NODES / 32) * 4;
    size_t OFF_G   = OFF_S + (size_t)N_NODES * 4;
    size_t OFF_H1T = OFF_G + (size_t)N_NODES * 256 * 4;
    size_t OFF_G2  = OFF_H1T + (size_t)N_NODES * 256 * 4;

    float*    agg   = (float*)(ws + OFF_AGG);
    uint32_t* hist1 = (uint32_t*)(ws + OFF_H1);
    uint32_t* hist2 = (uint32_t*)(ws + OFF_H2);
    uint32_t* hist3 = (uint32_t*)(ws + OFF_H3);
    uint32_t* sel   = (uint32_t*)(ws + OFF_SEL);
    uint32_t* Bm    = (uint32_t*)(ws + OFF_B);
    float*    s     = (float*)(ws + OFF_S);
    float*    g     = (float*)(ws + OFF_G);
    float*    h1    = (float*)(ws + OFF_H1T);
    float*    g2    = (float*)(ws + OFF_G2);

    // hist1|hist2|hist3 contiguous -> one memset; mgt (sel[6]) init to 0xFFFFFFFF
    hipMemsetAsync(hist1, 0, 4096 * 4 + 4096 * 4 + 1024, stream);
    hipMemsetAsync(&sel[6], 0xFF, 4, stream);

    agg_kernel<<<1024, 256, 0, stream>>>(attn, aggw, aggb, agg, hist1);
    scan_kernel<1><<<1, 256, 0, stream>>>(hist1, sel);
    hist2_kernel<<<512, 256, 0, stream>>>(agg, sel, hist2);
    scan_kernel<2><<<1, 256, 0, stream>>>(hist2, sel);
    passC_kernel<<<512, 256, 0, stream>>>(agg, sel, hist3);
    scan3_kernel<<<1, 256, 0, stream>>>(hist3, sel);

    maskB_kernel<<<dim3(64, 64), 256, 0, stream>>>(agg, sel, Bm);
    degs_kernel<<<N_NODES / 4, 256, 0, stream>>>(Bm, s);

    gemm1_kernel<<<256, 256, 0, stream>>>(x, W1, s, g);
    spmm1_kernel<<<N_NODES, 64, 0, stream>>>(Bm, g, s, b1, h1);
    gemm2_kernel<<<256, 128, 0, stream>>>(h1, W2, s, g2);
    spmm2_kernel<<<N_NODES, 64, 0, stream>>>(Bm, g2, s, b2, out);
}

// Round 3
// 432.370 us; speedup vs baseline: 1.4183x; 1.0193x over previous
//
#include <hip/hip_runtime.h>
#include <stdint.h>

#define N_NODES 4096
#define NNN ((int64_t)N_NODES * (int64_t)N_NODES)
#define TOTAL4 (NNN / 4)
#define NC 12
// floor(0.9 * (N*N - 1)) = 15099493 (frac = 0.5)
#define K0_RANK 15099493u

static __device__ __forceinline__ uint32_t f2key(float f) {
    uint32_t x = __float_as_uint(f);
    return (x & 0x80000000u) ? ~x : (x | 0x80000000u);
}
static __device__ __forceinline__ float key2f(uint32_t k) {
    uint32_t x = (k & 0x80000000u) ? (k & 0x7FFFFFFFu) : ~k;
    return __uint_as_float(x);
}

// 256-thread block-wide select: find bin b and residual rank such that the
// cumulative count over hist[0..b) <= target < ..+hist[b]. out[0]=bin, out[1]=rank.
static __device__ __forceinline__ void select_bin(const uint32_t* __restrict__ gh,
        int nb, uint32_t target, uint32_t* hl, uint32_t* sc, uint32_t* out) {
    int t = threadIdx.x;
    int per = nb >> 8;
    for (int i = t; i < nb; i += 256) hl[i] = gh[i];
    __syncthreads();
    uint32_t p = 0;
    for (int i = 0; i < per; ++i) p += hl[t * per + i];
    sc[t] = p;
    __syncthreads();
    for (int d = 1; d < 256; d <<= 1) {
        uint32_t v = (t >= d) ? sc[t - d] : 0u;
        __syncthreads();
        sc[t] += v;
        __syncthreads();
    }
    uint32_t excl = sc[t] - p;
    if (p > 0 && target >= excl && target < excl + p) {
        uint32_t cum = excl; int b = t * per;
        while (cum + hl[b] <= target) { cum += hl[b]; ++b; }
        out[0] = (uint32_t)b; out[1] = target - cum;
    }
    __syncthreads();
}

// ---------------------------------------------------------------------------
// 1) agg = sum_c w[c]*attn[c] + b ; per-block 4096-bin hist -> private slice
// ---------------------------------------------------------------------------
__global__ __launch_bounds__(256) void agg_kernel(const float* __restrict__ attn,
        const float* __restrict__ w, const float* __restrict__ bb,
        float* __restrict__ agg, uint32_t* __restrict__ slice) {
    __shared__ uint32_t h[4096];
    for (int i = threadIdx.x; i < 4096; i += 256) h[i] = 0;
    float wr[NC];
#pragma unroll
    for (int c = 0; c < NC; ++c) wr[c] = w[c];
    float b0 = bb[0];
    __syncthreads();
    const float4* a4 = (const float4*)attn;
    float4* o4 = (float4*)agg;
    for (int64_t i = (int64_t)blockIdx.x * 256 + threadIdx.x; i < TOTAL4; i += (int64_t)1024 * 256) {
        float ax = b0, ay = b0, az = b0, aw = b0;
#pragma unroll
        for (int c = 0; c < NC; ++c) {
            float4 t = a4[(int64_t)c * TOTAL4 + i];
            ax += wr[c] * t.x; ay += wr[c] * t.y; az += wr[c] * t.z; aw += wr[c] * t.w;
        }
        o4[i] = make_float4(ax, ay, az, aw);
        atomicAdd(&h[f2key(ax) >> 20], 1u);
        atomicAdd(&h[f2key(ay) >> 20], 1u);
        atomicAdd(&h[f2key(az) >> 20], 1u);
        atomicAdd(&h[f2key(aw) >> 20], 1u);
    }
    __syncthreads();
    uint32_t* dst = slice + (size_t)blockIdx.x * 4096;
    for (int i = threadIdx.x; i < 4096; i += 256) dst[i] = h[i];
}

// sum the 1024 slices -> hist1 (full overwrite, no memset needed)
__global__ void reduce1_kernel(const uint32_t* __restrict__ slice, uint32_t* __restrict__ hist1) {
    int b = blockIdx.x * 64 + threadIdx.x;
    uint32_t sum = 0;
    for (int j = 0; j < 1024; ++j) sum += slice[(size_t)j * 4096 + b];
    hist1[b] = sum;
}

// ---------------------------------------------------------------------------
// 2) level-2 hist (bits 19..8 within selected level-1 bin); inline select1
// ---------------------------------------------------------------------------
__global__ __launch_bounds__(256) void hist2_kernel(const float* __restrict__ agg,
        const uint32_t* __restrict__ hist1, uint32_t* __restrict__ hist2g) {
    __shared__ uint32_t hl[4096];
    __shared__ uint32_t sc[256];
    __shared__ uint32_t res[2];
    select_bin(hist1, 4096, K0_RANK, hl, sc, res);
    uint32_t p1 = res[0];
    for (int i = threadIdx.x; i < 4096; i += 256) hl[i] = 0;
    __syncthreads();
    const float4* a4 = (const float4*)agg;
#define PROC2(val) { uint32_t k = f2key(val); if ((k >> 20) == p1) atomicAdd(&hl[(k >> 8) & 0xFFFu], 1u); }
    for (int64_t i = (int64_t)blockIdx.x * 1024 + threadIdx.x; i < TOTAL4; i += (int64_t)1024 * 1024) {
        float4 v0 = a4[i], v1 = a4[i + 256], v2 = a4[i + 512], v3 = a4[i + 768];
        PROC2(v0.x) PROC2(v0.y) PROC2(v0.z) PROC2(v0.w)
        PROC2(v1.x) PROC2(v1.y) PROC2(v1.z) PROC2(v1.w)
        PROC2(v2.x) PROC2(v2.y) PROC2(v2.z) PROC2(v2.w)
        PROC2(v3.x) PROC2(v3.y) PROC2(v3.z) PROC2(v3.w)
    }
    __syncthreads();
    for (int i = threadIdx.x; i < 4096; i += 256) {
        uint32_t c = hl[i];
        if (c) atomicAdd(&hist2g[i], c);
    }
}

// ---------------------------------------------------------------------------
// 3) passC: level-3 hist (low 8 bits within prefix24) + min key above prefix24
// ---------------------------------------------------------------------------
__global__ __launch_bounds__(256) void passC_kernel(const float* __restrict__ agg,
        const uint32_t* __restrict__ hist1, const uint32_t* __restrict__ hist2g,
        uint32_t* __restrict__ hist3, uint32_t* __restrict__ sel) {
    __shared__ uint32_t hl[4096];
    __shared__ uint32_t sc[256];
    __shared__ uint32_t res[2];
    __shared__ uint32_t ms;
    select_bin(hist1, 4096, K0_RANK, hl, sc, res);
    uint32_t p1 = res[0], r1 = res[1];
    select_bin(hist2g, 4096, r1, hl, sc, res);
    uint32_t p24 = (p1 << 12) | res[0];
    sc[threadIdx.x] = 0;
    if (threadIdx.x == 0) ms = 0xFFFFFFFFu;
    __syncthreads();
    uint32_t mn = 0xFFFFFFFFu;
    const float4* a4 = (const float4*)agg;
#define PROCC(val) { uint32_t k = f2key(val); uint32_t hi = k >> 8; \
    if (hi == p24) atomicAdd(&sc[k & 0xFFu], 1u); else if (hi > p24) mn = min(mn, k); }
    for (int64_t i = (int64_t)blockIdx.x * 1024 + threadIdx.x; i < TOTAL4; i += (int64_t)1024 * 1024) {
        float4 v0 = a4[i], v1 = a4[i + 256], v2 = a4[i + 512], v3 = a4[i + 768];
        PROCC(v0.x) PROCC(v0.y) PROCC(v0.z) PROCC(v0.w)
        PROCC(v1.x) PROCC(v1.y) PROCC(v1.z) PROCC(v1.w)
        PROCC(v2.x) PROCC(v2.y) PROCC(v2.z) PROCC(v2.w)
        PROCC(v3.x) PROCC(v3.y) PROCC(v3.z) PROCC(v3.w)
    }
    atomicMin(&ms, mn);
    __syncthreads();
    uint32_t c = sc[threadIdx.x];
    if (c) atomicAdd(&hist3[threadIdx.x], c);
    if (threadIdx.x == 0) atomicMin(&sel[6], ms);
}

// ---------------------------------------------------------------------------
// finalize: recompute selects, walk hist3, write thresh to sel[7]
// ---------------------------------------------------------------------------
__global__ void finalize_kernel(const uint32_t* __restrict__ hist1,
        const uint32_t* __restrict__ hist2g, const uint32_t* __restrict__ hist3,
        uint32_t* __restrict__ sel) {
    __shared__ uint32_t hl[4096];
    __shared__ uint32_t sc[256];
    __shared__ uint32_t res[2];
    select_bin(hist1, 4096, K0_RANK, hl, sc, res);
    uint32_t p1 = res[0], r1 = res[1];
    select_bin(hist2g, 4096, r1, hl, sc, res);
    uint32_t p2 = res[0], r2 = res[1];
    if (threadIdx.x < 256) hl[threadIdx.x] = hist3[threadIdx.x];
    __syncthreads();
    if (threadIdx.x == 0) {
        uint32_t p24 = (p1 << 12) | p2;
        uint32_t cum = 0; int b = 0;
        while (cum + hl[b] <= r2) { cum += hl[b]; ++b; }
        uint32_t key0 = (p24 << 8) | (uint32_t)b;
        uint32_t count_le = K0_RANK - r2 + cum + hl[b];
        uint32_t key1;
        if (count_le >= K0_RANK + 2u) key1 = key0;
        else {
            int nb = b + 1;
            while (nb < 256 && hl[nb] == 0) ++nb;
            key1 = (nb < 256) ? ((p24 << 8) | (uint32_t)nb) : sel[6];
        }
        float v0 = key2f(key0);
        float v1 = key2f(key1);
        ((float*)sel)[7] = v0 + 0.5f * (v1 - v0);   // same formula as R1/R2 (passed)
    }
}

// ---------------------------------------------------------------------------
// 4) B[v][u] bitmask of A^T (A = mask | I) + fused deg atomics
// ---------------------------------------------------------------------------
__global__ __launch_bounds__(256) void maskB_kernel(const float* __restrict__ agg,
        const uint32_t* __restrict__ sel, uint32_t* __restrict__ B,
        uint32_t* __restrict__ deg) {
    __shared__ uint32_t tile[64][2];
    const float thresh = __uint_as_float(sel[7]);
    int u0 = blockIdx.x * 64, v0 = blockIdx.y * 64;
    int wave = threadIdx.x >> 6, lane = threadIdx.x & 63;
    for (int i = 0; i < 16; ++i) {
        int r = wave * 16 + i;
        int u = u0 + r, v = v0 + lane;
        float val = agg[(int64_t)u * N_NODES + v];
        bool pred = (val >= thresh) || (u == v);
        unsigned long long bm = __ballot(pred ? 1 : 0);
        if (lane == 0) { tile[r][0] = (uint32_t)bm; tile[r][1] = (uint32_t)(bm >> 32); }
    }
    __syncthreads();
    int t = threadIdx.x;
    if (t < 64) {
        int v = v0 + t;
        int sh = t & 31, hw = t >> 5;
        uint32_t w0 = 0, w1 = 0;
#pragma unroll
        for (int i = 0; i < 32; ++i) {
            w0 |= ((tile[i][hw] >> sh) & 1u) << i;
            w1 |= ((tile[32 + i][hw] >> sh) & 1u) << i;
        }
        B[(int64_t)v * (N_NODES / 32) + (u0 >> 5)]     = w0;
        B[(int64_t)v * (N_NODES / 32) + (u0 >> 5) + 1] = w1;
        atomicAdd(&deg[v], (uint32_t)(__popc(w0) + __popc(w1)));
    }
}

// ---------------------------------------------------------------------------
// 5) gemms: 8 rows/block, float4 LDS reads, k-unroll 4
// ---------------------------------------------------------------------------
__global__ __launch_bounds__(256) void gemm1_kernel(const float* __restrict__ x,
        const float* __restrict__ W1, const uint32_t* __restrict__ deg,
        float* __restrict__ g) {
    __shared__ float xr[8 * 128];
    __shared__ float sr[8];
    int u0 = blockIdx.x * 8;
    int t = threadIdx.x;
    ((float4*)xr)[t] = ((const float4*)(x + (int64_t)u0 * 128))[t];  // 256 float4
    if (t < 8) sr[t] = rsqrtf((float)deg[u0 + t]);
    __syncthreads();
    float acc[8] = {0, 0, 0, 0, 0, 0, 0, 0};
    for (int k = 0; k < 128; k += 4) {
        float w0 = W1[(k + 0) * 256 + t], w1 = W1[(k + 1) * 256 + t];
        float w2 = W1[(k + 2) * 256 + t], w3 = W1[(k + 3) * 256 + t];
#pragma unroll
        for (int r = 0; r < 8; ++r) {
            float4 xv = *(const float4*)&xr[r * 128 + k];
            acc[r] += xv.x * w0 + xv.y * w1 + xv.z * w2 + xv.w * w3;
        }
    }
#pragma unroll
    for (int r = 0; r < 8; ++r)
        g[(int64_t)(u0 + r) * 256 + t] = sr[r] * acc[r];
}

__global__ __launch_bounds__(256) void gemm2_kernel(const float* __restrict__ h1,
        const float* __restrict__ W2, const uint32_t* __restrict__ deg,
        float* __restrict__ g2) {
    __shared__ float hr[8 * 256];
    __shared__ float sr[8];
    int u0 = blockIdx.x * 8;
    int t = threadIdx.x;
    const float4* h4 = (const float4*)(h1 + (int64_t)u0 * 256);
    ((float4*)hr)[t] = h4[t];
    ((float4*)hr)[t + 256] = h4[t + 256];
    if (t < 8) sr[t] = rsqrtf((float)deg[u0 + t]);
    __syncthreads();
    int col = t & 127;
    int roff = (t >> 7) * 4;
    float acc[4] = {0, 0, 0, 0};
    for (int k = 0; k < 256; k += 4) {
        float w0 = W2[(k + 0) * 128 + col], w1 = W2[(k + 1) * 128 + col];
        float w2 = W2[(k + 2) * 128 + col], w3 = W2[(k + 3) * 128 + col];
#pragma unroll
        for (int r = 0; r < 4; ++r) {
            float4 hv = *(const float4*)&hr[(roff + r) * 256 + k];
            acc[r] += hv.x * w0 + hv.y * w1 + hv.z * w2 + hv.w * w3;
        }
    }
#pragma unroll
    for (int r = 0; r < 4; ++r)
        g2[(int64_t)(u0 + roff + r) * 128 + col] = sr[roff + r] * acc[r];
}

// ---------------------------------------------------------------------------
// 6) spmm: decode bitmask once into LDS idx list, then float4 gathers
// ---------------------------------------------------------------------------
static __device__ __forceinline__ uint32_t build_idx(const uint32_t* __restrict__ B,
                                                     int v, int t, uint16_t* idx) {
    const uint32_t* row = B + (int64_t)v * 128;
    uint32_t w0 = row[t], w1 = row[t + 64];
    uint32_t pc0 = __popc(w0), pc1 = __popc(w1);
    int s0 = (int)pc0, s1 = (int)pc1;
#pragma unroll
    for (int d = 1; d < 64; d <<= 1) {
        int a = __shfl_up(s0, d);
        int b = __shfl_up(s1, d);
        if (t >= d) { s0 += a; s1 += b; }
    }
    uint32_t tot0 = (uint32_t)__shfl(s0, 63);
    uint32_t cnt  = tot0 + (uint32_t)__shfl(s1, 63);
    uint32_t p = (uint32_t)s0 - pc0;
    uint32_t m = w0;
    int ub = t * 32;
    while (m) { int bi = __ffs(m) - 1; m &= m - 1; idx[p++] = (uint16_t)(ub + bi); }
    p = tot0 + (uint32_t)s1 - pc1;
    m = w1;
    ub = (t + 64) * 32;
    while (m) { int bi = __ffs(m) - 1; m &= m - 1; idx[p++] = (uint16_t)(ub + bi); }
    __syncthreads();
    return cnt;
}

__global__ __launch_bounds__(64) void spmm1_kernel(const uint32_t* __restrict__ B,
        const float* __restrict__ g, const uint32_t* __restrict__ deg,
        const float* __restrict__ b1, float* __restrict__ h1) {
    __shared__ uint16_t idx[4096];
    int v = blockIdx.x;
    int t = threadIdx.x;
    uint32_t cnt = build_idx(B, v, t, idx);
    const float4* g4 = (const float4*)g;
    float4 acc = make_float4(0.f, 0.f, 0.f, 0.f);
    uint32_t i = 0;
    for (; i + 8 <= cnt; i += 8) {
        float4 a0 = g4[idx[i + 0] * 64 + t];
        float4 a1 = g4[idx[i + 1] * 64 + t];
        float4 a2 = g4[idx[i + 2] * 64 + t];
        float4 a3 = g4[idx[i + 3] * 64 + t];
        float4 a4 = g4[idx[i + 4] * 64 + t];
        float4 a5 = g4[idx[i + 5] * 64 + t];
        float4 a6 = g4[idx[i + 6] * 64 + t];
        float4 a7 = g4[idx[i + 7] * 64 + t];
        acc.x += ((a0.x + a1.x) + (a2.x + a3.x)) + ((a4.x + a5.x) + (a6.x + a7.x));
        acc.y += ((a0.y + a1.y) + (a2.y + a3.y)) + ((a4.y + a5.y) + (a6.y + a7.y));
        acc.z += ((a0.z + a1.z) + (a2.z + a3.z)) + ((a4.z + a5.z) + (a6.z + a7.z));
        acc.w += ((a0.w + a1.w) + (a2.w + a3.w)) + ((a4.w + a5.w) + (a6.w + a7.w));
    }
    for (; i < cnt; ++i) {
        float4 a = g4[idx[i] * 64 + t];
        acc.x += a.x; acc.y += a.y; acc.z += a.z; acc.w += a.w;
    }
    float sv = rsqrtf((float)deg[v]);
    float4 bb = ((const float4*)b1)[t];
    float4 r;
    r.x = fmaxf(sv * acc.x + bb.x, 0.f);
    r.y = fmaxf(sv * acc.y + bb.y, 0.f);
    r.z = fmaxf(sv * acc.z + bb.z, 0.f);
    r.w = fmaxf(sv * acc.w + bb.w, 0.f);
    ((float4*)h1)[(int64_t)v * 64 + t] = r;
}

__global__ __launch_bounds__(64) void spmm2_kernel(const uint32_t* __restrict__ B,
        const float* __restrict__ g2, const uint32_t* __restrict__ deg,
        const float* __restrict__ b2, float* __restrict__ out) {
    __shared__ uint16_t idx[4096];
    int v = blockIdx.x;
    int t = threadIdx.x;
    uint32_t cnt = build_idx(B, v, t, idx);
    const float4* g4 = (const float4*)g2;
    int jg = t & 31;
    uint32_t i = (uint32_t)(t >> 5);
    float4 acc = make_float4(0.f, 0.f, 0.f, 0.f);
    for (; i + 6 < cnt; i += 8) {
        float4 a0 = g4[idx[i + 0] * 32 + jg];
        float4 a1 = g4[idx[i + 2] * 32 + jg];
        float4 a2 = g4[idx[i + 4] * 32 + jg];
        float4 a3 = g4[idx[i + 6] * 32 + jg];
        acc.x += (a0.x + a1.x) + (a2.x + a3.x);
        acc.y += (a0.y + a1.y) + (a2.y + a3.y);
        acc.z += (a0.z + a1.z) + (a2.z + a3.z);
        acc.w += (a0.w + a1.w) + (a2.w + a3.w);
    }
    for (; i < cnt; i += 2) {
        float4 a = g4[idx[i] * 32 + jg];
        acc.x += a.x; acc.y += a.y; acc.z += a.z; acc.w += a.w;
    }
    acc.x += __shfl_xor(acc.x, 32);
    acc.y += __shfl_xor(acc.y, 32);
    acc.z += __shfl_xor(acc.z, 32);
    acc.w += __shfl_xor(acc.w, 32);
    if (t < 32) {
        float sv = rsqrtf((float)deg[v]);
        float4 bb = ((const float4*)b2)[jg];
        float4 r;
        r.x = sv * acc.x + bb.x;
        r.y = sv * acc.y + bb.y;
        r.z = sv * acc.z + bb.z;
        r.w = sv * acc.w + bb.w;
        ((float4*)out)[(int64_t)v * 32 + jg] = r;
    }
}

// ---------------------------------------------------------------------------
extern "C" void kernel_launch(void* const* d_in, const int* in_sizes, int n_in,
                              void* d_out, int out_size, void* d_ws, size_t ws_size,
                              hipStream_t stream) {
    const float* x    = (const float*)d_in[0];
    const float* attn = (const float*)d_in[1];
    const float* aggw = (const float*)d_in[2];
    const float* aggb = (const float*)d_in[3];
    const float* W1   = (const float*)d_in[4];
    const float* b1   = (const float*)d_in[5];
    const float* W2   = (const float*)d_in[6];
    const float* b2   = (const float*)d_in[7];
    float* out = (float*)d_out;

    char* ws = (char*)d_ws;
    size_t OFF_AGG   = 0;
    size_t OFF_SLICE = OFF_AGG + (size_t)NNN * 4;                 // 16 MB of slices
    size_t OFF_H1    = OFF_SLICE + (size_t)1024 * 4096 * 4;
    size_t OFF_H2    = OFF_H1 + 4096 * 4;
    size_t OFF_H3    = OFF_H2 + 4096 * 4;
    size_t OFF_DEG   = OFF_H3 + 1024;
    size_t OFF_SEL   = OFF_DEG + 4096 * 4;
    size_t OFF_B     = OFF_SEL + 256;
    size_t OFF_G     = OFF_B + (size_t)N_NODES * (N_NODES / 32) * 4;
    size_t OFF_H1T   = OFF_G + (size_t)N_NODES * 256 * 4;
    size_t OFF_G2    = OFF_H1T + (size_t)N_NODES * 256 * 4;

    float*    agg   = (float*)(ws + OFF_AGG);
    uint32_t* slice = (uint32_t*)(ws + OFF_SLICE);
    uint32_t* hist1 = (uint32_t*)(ws + OFF_H1);
    uint32_t* hist2 = (uint32_t*)(ws + OFF_H2);
    uint32_t* hist3 = (uint32_t*)(ws + OFF_H3);
    uint32_t* deg   = (uint32_t*)(ws + OFF_DEG);
    uint32_t* sel   = (uint32_t*)(ws + OFF_SEL);
    uint32_t* Bm    = (uint32_t*)(ws + OFF_B);
    float*    g     = (float*)(ws + OFF_G);
    float*    h1    = (float*)(ws + OFF_H1T);
    float*    g2    = (float*)(ws + OFF_G2);

    // zero hist2|hist3|deg (contiguous) each call; sel[6] = 0xFFFFFFFF
    hipMemsetAsync(hist2, 0, 4096 * 4 + 1024 + 4096 * 4, stream);
    hipMemsetAsync(&sel[6], 0xFF, 4, stream);

    agg_kernel<<<1024, 256, 0, stream>>>(attn, aggw, aggb, agg, slice);
    reduce1_kernel<<<64, 64, 0, stream>>>(slice, hist1);
    hist2_kernel<<<1024, 256, 0, stream>>>(agg, hist1, hist2);
    passC_kernel<<<1024, 256, 0, stream>>>(agg, hist1, hist2, hist3, sel);
    finalize_kernel<<<1, 256, 0, stream>>>(hist1, hist2, hist3, sel);

    maskB_kernel<<<dim3(64, 64), 256, 0, stream>>>(agg, sel, Bm, deg);

    gemm1_kernel<<<512, 256, 0, stream>>>(x, W1, deg, g);
    spmm1_kernel<<<N_NODES, 64, 0, stream>>>(Bm, g, deg, b1, h1);
    gemm2_kernel<<<512, 256, 0, stream>>>(h1, W2, deg, g2);
    spmm2_kernel<<<N_NODES, 64, 0, stream>>>(Bm, g2, deg, b2, out);
}